// Round 1
// 1087.169 us; speedup vs baseline: 1.2404x; 1.2404x over previous
//
#include <hip/hip_runtime.h>
#include <hip/hip_bf16.h>

// Round theory: VALU-bound (52.7% busy, MFMA 13%) + 1.23e8 LDS-conflict cycles (~16%).
// 1) W/Wc split-bf16 conversion hoisted into a pre-kernel (0.78 MB ws images, swizzled,
//    staged with global_load_lds). 2) v_cvt_pk_bf16_f32 for all remaining conversions.
// 3) conflict-free layouts: x/W 128B rows + XOR swizzle; vT 208B stride; phase-4 row remap.
// Predicted: VALUBusy ~37%, conflicts <4e7, dur 1213 -> ~900us.

constexpr int T  = 6;
constexpr int S  = 66;    // 3*J
constexpr int IN = 256;
constexpr int H  = 8;
constexpr int D  = 32;
constexpr int J  = 22;
constexpr float NEG = -9e15f;
constexpr float INV_SQRT_D = 0.17677669529663688110f; // 1/sqrt(32)

// ---------------- LDS map (bytes), SMEM 50,008 -> 3 blocks/CU (<=53,248) -------------
// proj stage (per 64-K chunk, x4): xh/xl 80x128B @0/10,240; wh/wl 96x128B @20,480/32,768
//   (end 45,056). Rows XOR-swizzled: byte ^= (row&7)<<4.
// attn persistent:
//   qh/ql bf16[66][36] @0/4,752     kh/kl @9,504/14,256 (end 19,008; 72B rows, 8B align)
//   sc f32[66][66] @19,008 (end 36,432)
//   vTh/vTl bf16[32][104] @36,432/43,088 (208B rows, end 49,744)
//   inv f32[66] @49,744 (end 50,008)
// softmax->PV overlays: Ph/Pl bf16[66][104] @0/13,728 (end 27,456); aoT bf16[32][104] @27,456
// phase-6 overlays (vT dead): Wch/Wcl bf16[32][104] @36,432/43,088
#define XH_OFF   0
#define XL_OFF   10240
#define WH_OFF   20480
#define WL_OFF   32768
#define QH_OFF   0
#define QL_OFF   4752
#define KH_OFF   9504
#define KL_OFF   14256
#define SC_OFF   19008
#define VTH_OFF  36432
#define VTL_OFF  43088
#define INV_OFF  49744
#define PH_OFF   0
#define PL_OFF   13728
#define AOT_OFF  27456
#define WCH_OFF  36432
#define WCL_OFF  43088
#define SMEM_BYTES 50008

// ws layout: 32 images (h*4+chunk) of [hi 96x128B | lo 96x128B] = 24,576 each -> 786,432
// then Wc image [hi 32x208B | lo 32x208B] = 13,312. Total 799,744.
#define WSW_STRIDE 24576
#define WSWC_OFF   786432
#define WS_BYTES   799744

typedef float f32x4  __attribute__((ext_vector_type(4)));
typedef short bf16x8 __attribute__((ext_vector_type(8)));
typedef short s4v    __attribute__((ext_vector_type(4)));

__device__ __forceinline__ unsigned cvtpk(float a, float b) {
    unsigned r;
    asm("v_cvt_pk_bf16_f32 %0, %1, %2" : "=v"(r) : "v"(a), "v"(b));
    return r;   // low16 = bf16(a), high16 = bf16(b), RNE
}
__device__ __forceinline__ float bfh2f(unsigned short h) {
    return __uint_as_float(((unsigned)h) << 16);
}
// split two f32 into packed bf16 hi (rne) and bf16 lo (rne of residual) — 6 VALU
__device__ __forceinline__ void split2(float a, float b, unsigned& hi, unsigned& lo) {
    unsigned h = cvtpk(a, b);
    float ra = a - __uint_as_float(h << 16);
    float rb = b - __uint_as_float(h & 0xffff0000u);
    lo = cvtpk(ra, rb);
    hi = h;
}
// load 8 bf16 from an 8-byte-aligned LDS address as two b64 reads
__device__ __forceinline__ bf16x8 ld_bf16x8_a8(const short* p) {
    s4v a = *(const s4v*)p;
    s4v b = *(const s4v*)(p + 4);
    return __builtin_shufflevector(a, b, 0, 1, 2, 3, 4, 5, 6, 7);
}
// async global->LDS, 16B/lane; lds base wave-uniform (HW adds lane*16)
__device__ __forceinline__ void gload16(const void* g, void* l) {
    __builtin_amdgcn_global_load_lds(
        (const __attribute__((address_space(1))) unsigned*)g,
        (__attribute__((address_space(3))) unsigned*)l, 16, 0, 0);
}

// ---------------- pre-kernel: split W(h,chunk) images + Wc image into ws -------------
__global__ __launch_bounds__(256)
void presplit_kernel(const float* __restrict__ Wq, const float* __restrict__ Wk,
                     const float* __restrict__ Wv, const float* __restrict__ Wc,
                     unsigned char* __restrict__ ws)
{
    int gid = blockIdx.x * 256 + threadIdx.x;
    if (gid < 49152) {                     // 8h x 4chunk x 96rows x 16 col-groups
        int c   = gid & 15;
        int r2  = gid >> 4;
        int row = r2 % 96;
        int r3  = r2 / 96;                 // h*4 + chunk
        int mat = row >> 5, dd = row & 31;
        int chunk = r3 & 3, hh = r3 >> 2;
        const float* Wm = (mat == 0) ? Wq : (mat == 1) ? Wk : Wv;
        float4 v = *(const float4*)(Wm + (size_t)(hh * 32 + dd) * IN + chunk * 64 + c * 4);
        uint2 hi, lo;
        split2(v.x, v.y, hi.x, lo.x);
        split2(v.z, v.w, hi.y, lo.y);
        unsigned base = (unsigned)r3 * WSW_STRIDE;
        unsigned rel  = (unsigned)(((row << 7) + (c << 3)) ^ ((row & 7) << 4));
        *(uint2*)(ws + base + rel)         = hi;
        *(uint2*)(ws + base + 12288 + rel) = lo;
    } else if (gid < 49152 + 1664) {       // Wc image: 32 rows x 52 dword cols (zero-padded)
        int g2  = gid - 49152;
        int row = g2 / 52, cu = g2 - row * 52;
        int c0  = 2 * cu;
        float a = (row < 22 && c0     < 66) ? Wc[row * 66 + c0]     : 0.f;
        float b = (row < 22 && c0 + 1 < 66) ? Wc[row * 66 + c0 + 1] : 0.f;
        unsigned hi, lo;
        split2(a, b, hi, lo);
        *(unsigned*)(ws + WSWC_OFF + row * 208 + 4 * cu)        = hi;
        *(unsigned*)(ws + WSWC_OFF + 6656 + row * 208 + 4 * cu) = lo;
    }
}

template<bool PRESPLIT>
__global__ __launch_bounds__(256, 3)
void mha_fused_kernel(const float* __restrict__ x,
                      const float* __restrict__ Wq, const float* __restrict__ bq,
                      const float* __restrict__ Wk, const float* __restrict__ bk,
                      const float* __restrict__ Wv, const float* __restrict__ bv,
                      const float* __restrict__ Wc, const float* __restrict__ bc,
                      const unsigned char* __restrict__ ws,
                      float* __restrict__ out)
{
    __shared__ __align__(16) unsigned char smem[SMEM_BYTES];

    const int tid = threadIdx.x;
    const int bth = blockIdx.x;          // [0, 512*6*8)
    const int h   = bth & 7;
    const int bt  = bth >> 3;            // b*T + t

    const int wid  = tid >> 6;           // wave 0..3
    const int lane = tid & 63;
    const int l15  = lane & 15;
    const int quad = lane >> 4;
    const int swz  = (l15 & 7) << 4;     // XOR swizzle for 128B-row tiles

    // ---------------- Phase 1: q,k,v projections via split-bf16 MFMA ------------------
    f32x4 accs[8];
    #pragma unroll
    for (int jj = 0; jj < 8; ++jj) accs[jj] = (f32x4){0.f, 0.f, 0.f, 0.f};

    for (int chunk = 0; chunk < 4; ++chunk) {    // K = 4 x 64
        __syncthreads();
        if constexpr (PRESPLIT) {
            // W slices: pre-split swizzled image, direct global->LDS (24 KiB, 24 instrs)
            const unsigned char* wimg = ws + (unsigned)((h << 2) | chunk) * WSW_STRIDE;
            for (int i = wid; i < 24; i += 4)
                gload16(wimg + (i << 10) + (lane << 4), smem + WH_OFF + (i << 10));
        } else {
            for (int u = tid; u < 1536; u += 256) {   // W slices: 96 x 64, inline split
                int row = u >> 4, c = u & 15;
                int mat = row >> 5, dd = row & 31;
                const float* Wm = (mat == 0) ? Wq : (mat == 1) ? Wk : Wv;
                float4 v = *(const float4*)(Wm + (size_t)(h * 32 + dd) * IN + chunk * 64 + c * 4);
                uint2 hi, lo;
                split2(v.x, v.y, hi.x, lo.x);
                split2(v.z, v.w, hi.y, lo.y);
                int rel = ((row << 7) + (c << 3)) ^ ((row & 7) << 4);
                *(uint2*)(smem + WH_OFF + rel) = hi;
                *(uint2*)(smem + WL_OFF + rel) = lo;
            }
        }
        {   // x tile: 66 x 64 f32 -> hi/lo bf16, swizzled 128B rows
            const float* xg = x + (size_t)bt * S * IN + chunk * 64;
            for (int u = tid; u < 1056; u += 256) {
                int s = u >> 4, c = u & 15;
                float4 v = *(const float4*)(xg + (size_t)s * IN + c * 4);
                uint2 hi, lo;
                split2(v.x, v.y, hi.x, lo.x);
                split2(v.z, v.w, hi.y, lo.y);
                int rel = ((s << 7) + (c << 3)) ^ ((s & 7) << 4);
                *(uint2*)(smem + XH_OFF + rel) = hi;
                *(uint2*)(smem + XL_OFF + rel) = lo;
            }
        }
        __syncthreads();

        const unsigned char* sb = smem;
        for (int jj = 0; jj < 8; ++jj) {
            int j = wid + 4 * jj;
            if (j >= 30) break;                      // wave-uniform
            int mat = j / 10, rr = j - mat * 10;
            int mtile = rr >> 1, ntile = rr & 1;
            int abase = XH_OFF + ((mtile * 16 + l15) << 7);
            int bbase = WH_OFF + (((mat << 5) + (ntile << 4) + l15) << 7);
            #pragma unroll
            for (int kk = 0; kk < 2; ++kk) {
                int off = ((quad << 4) + (kk << 6)) ^ swz;
                bf16x8 ah = *(const bf16x8*)(sb + abase + off);
                bf16x8 al = *(const bf16x8*)(sb + abase + 10240 + off);  // XL = XH+10240
                bf16x8 bh = *(const bf16x8*)(sb + bbase + off);
                bf16x8 bl = *(const bf16x8*)(sb + bbase + 12288 + off);  // WL = WH+12288
                accs[jj] = __builtin_amdgcn_mfma_f32_16x16x32_bf16(ah, bh, accs[jj], 0, 0, 0);
                accs[jj] = __builtin_amdgcn_mfma_f32_16x16x32_bf16(ah, bl, accs[jj], 0, 0, 0);
                accs[jj] = __builtin_amdgcn_mfma_f32_16x16x32_bf16(al, bh, accs[jj], 0, 0, 0);
            }
        }
    }
    __syncthreads();   // stage dead; epilogue overwrites it

    // ---------------- Epilogue: q/k -> hi/lo [s][d]; v -> relu, hi/lo transposed [d][s]
    {
        short* qh = (short*)(smem + QH_OFF); short* ql = (short*)(smem + QL_OFF);
        short* kh = (short*)(smem + KH_OFF); short* kl = (short*)(smem + KL_OFF);
        for (int jj = 0; jj < 8; ++jj) {
            int j = wid + 4 * jj;
            if (j >= 30) break;
            int mat = j / 10, rr = j - mat * 10;
            int mtile = rr >> 1, ntile = rr & 1;
            int dd = ntile * 16 + l15;
            const float* bias_p = (mat == 0) ? bq : (mat == 1) ? bk : bv;
            float bias = bias_p[h * 32 + dd];
            int sbase = mtile * 16 + quad * 4;
            if (mat < 2) {
                short* bh_ = (mat == 0) ? qh : kh;
                short* bl_ = (mat == 0) ? ql : kl;
                uint2 hi, lo;
                split2(accs[jj][0] + bias, accs[jj][1] + bias, hi.x, lo.x);
                split2(accs[jj][2] + bias, accs[jj][3] + bias, hi.y, lo.y);
                unsigned hs[4] = { hi.x & 0xffffu, hi.x >> 16, hi.y & 0xffffu, hi.y >> 16 };
                unsigned ls[4] = { lo.x & 0xffffu, lo.x >> 16, lo.y & 0xffffu, lo.y >> 16 };
                #pragma unroll
                for (int reg = 0; reg < 4; ++reg) {
                    int s = sbase + reg;
                    if (s < 66) {
                        bh_[s * 36 + dd] = (short)hs[reg];
                        bl_[s * 36 + dd] = (short)ls[reg];
                    }
                }
            } else {
                float vv[4];
                #pragma unroll
                for (int reg = 0; reg < 4; ++reg) {
                    int s = sbase + reg;
                    vv[reg] = (s < 66) ? fmaxf(accs[jj][reg] + bias, 0.f) : 0.f; // zero K-pad
                }
                uint2 ph, pl;
                split2(vv[0], vv[1], ph.x, pl.x);
                split2(vv[2], vv[3], ph.y, pl.y);
                *(uint2*)(smem + VTH_OFF + dd * 208 + 2 * sbase) = ph;
                *(uint2*)(smem + VTL_OFF + dd * 208 + 2 * sbase) = pl;
            }
        }
        // zero vT cols 80..95 (beyond epilogue coverage; K-pad safety for PV)
        for (int u = tid; u < 512; u += 256) {
            int comp = u >= 256 ? 1 : 0, rem = comp ? u - 256 : u;
            int row = rem >> 3, kcol = 80 + 2 * (rem & 7);
            *(unsigned*)(smem + (comp ? VTL_OFF : VTH_OFF) + row * 208 + 2 * kcol) = 0u;
        }
    }
    __syncthreads();

    // ---------------- Phase 3: sc = mask * (q k^T) / sqrt(D) via split MFMA ----------
    {
        const short* qh = (const short*)(smem + QH_OFF);
        const short* ql = (const short*)(smem + QL_OFF);
        const short* kh = (const short*)(smem + KH_OFF);
        const short* kl = (const short*)(smem + KL_OFF);
        float* sc = (float*)(smem + SC_OFF);
        for (int t = 0; t < 7; ++t) {
            int tt = wid + 4 * t;
            if (tt >= 25) break;                 // wave-uniform
            int mq = tt / 5, mk = tt - mq * 5;
            int aoff = (mq * 16 + l15) * 36 + quad * 8;
            int boff = (mk * 16 + l15) * 36 + quad * 8;
            bf16x8 ah = ld_bf16x8_a8(qh + aoff);
            bf16x8 al = ld_bf16x8_a8(ql + aoff);
            bf16x8 bh = ld_bf16x8_a8(kh + boff);
            bf16x8 bl = ld_bf16x8_a8(kl + boff);
            f32x4 acc = (f32x4){0.f, 0.f, 0.f, 0.f};
            acc = __builtin_amdgcn_mfma_f32_16x16x32_bf16(ah, bh, acc, 0, 0, 0);
            acc = __builtin_amdgcn_mfma_f32_16x16x32_bf16(ah, bl, acc, 0, 0, 0);
            acc = __builtin_amdgcn_mfma_f32_16x16x32_bf16(al, bh, acc, 0, 0, 0);
            int ks = mk * 16 + l15;
            #pragma unroll
            for (int reg = 0; reg < 4; ++reg) {
                int qs = mq * 16 + quad * 4 + reg;
                if (qs < 66 && ks < 66) {
                    bool masked = (qs < J && ks >= 2 * J) || (qs >= 2 * J && ks < J);
                    sc[qs * 66 + ks] = masked ? 0.f : acc[reg] * INV_SQRT_D;
                }
            }
        }
    }
    __syncthreads();

    // ---------------- Phase 4: prune + softmax (16-lane groups, regs + shuffles) ------
    // Group->row remap: rows step by 4 within a wave -> sc reads land on banks {0,8,16,24}.
    {
        const float* sc = (const float*)(smem + SC_OFF);
        const int group = tid >> 4, lane16 = tid & 15;
        const int rbase = ((group & 3) << 2) + (group >> 2);   // bijection over [0,16)
        float val[5][5];
        #pragma unroll
        for (int i = 0; i < 5; ++i) {
            int r = rbase + 16 * i;
            #pragma unroll
            for (int tt = 0; tt < 5; ++tt) {
                int c = lane16 + 16 * tt;
                val[i][tt] = (r < 66 && c < 66) ? sc[r * 66 + c] : -INFINITY;
            }
        }
        __syncthreads();   // all sc reads done -> P may overlay sc front

        short* Ph = (short*)(smem + PH_OFF);
        short* Pl = (short*)(smem + PL_OFF);
        float* inv = (float*)(smem + INV_OFF);
        #pragma unroll
        for (int i = 0; i < 5; ++i) {
            int r = rbase + 16 * i;
            if (r >= 66) continue;               // group-uniform
            float m = -INFINITY;
            #pragma unroll
            for (int tt = 0; tt < 5; ++tt) m = fmaxf(m, val[i][tt]);
            m = fmaxf(m, __shfl_xor(m, 1));
            m = fmaxf(m, __shfl_xor(m, 2));
            m = fmaxf(m, __shfl_xor(m, 4));
            m = fmaxf(m, __shfl_xor(m, 8));
            const float thr = m / 9.0f;
            float e[6], lsum = 0.f, rmax = -INFINITY;
            e[5] = 0.f;
            #pragma unroll
            for (int tt = 0; tt < 5; ++tt) {
                float sv = val[i][tt];
                float pr = (fabsf(sv) <= thr) ? NEG : sv;   // -INF sentinels stay below
                val[i][tt] = pr;
                rmax = fmaxf(rmax, pr);
            }
            rmax = fmaxf(rmax, __shfl_xor(rmax, 1));
            rmax = fmaxf(rmax, __shfl_xor(rmax, 2));
            rmax = fmaxf(rmax, __shfl_xor(rmax, 4));
            rmax = fmaxf(rmax, __shfl_xor(rmax, 8));
            #pragma unroll
            for (int tt = 0; tt < 5; ++tt) {
                int c = lane16 + 16 * tt;
                float ev = (c < 66) ? __expf(val[i][tt] - rmax) : 0.f;
                e[tt] = ev;
                lsum += ev;
            }
            lsum += __shfl_xor(lsum, 1);
            lsum += __shfl_xor(lsum, 2);
            lsum += __shfl_xor(lsum, 4);
            lsum += __shfl_xor(lsum, 8);
            #pragma unroll
            for (int tt = 0; tt < 6; ++tt) {     // cols 0..95: data or zero pad
                int c = lane16 + 16 * tt;
                unsigned short hi = 0, lo = 0;
                if (c < 66) {
                    float ev = e[tt];
                    hi = (unsigned short)cvtpk(ev, ev);
                    lo = (unsigned short)cvtpk(ev - bfh2f(hi), 0.f);
                }
                if (c < 96) {
                    Ph[r * 104 + c] = (short)hi;
                    Pl[r * 104 + c] = (short)lo;
                }
            }
            if (lane16 == 0) inv[r] = 1.0f / lsum;
        }
    }
    __syncthreads();

    // ---------------- Phase 5: aoT = (P @ v)^T * inv, bf16-hi, via MFMA --------------
    {
        const short* Ph = (const short*)(smem + PH_OFF);
        const short* Pl = (const short*)(smem + PL_OFF);
        const short* vh = (const short*)(smem + VTH_OFF);
        const short* vl = (const short*)(smem + VTL_OFF);
        const float* inv = (const float*)(smem + INV_OFF);
        for (int t = 0; t < 3; ++t) {
            int tt = wid + 4 * t;
            if (tt >= 10) break;
            int mq = tt >> 1, nd = tt & 1;
            f32x4 acc = (f32x4){0.f, 0.f, 0.f, 0.f};
            #pragma unroll
            for (int ks = 0; ks < 3; ++ks) {
                bf16x8 a   = *(const bf16x8*)(Ph + (mq * 16 + l15) * 104 + ks * 32 + quad * 8);
                bf16x8 al8 = *(const bf16x8*)(Pl + (mq * 16 + l15) * 104 + ks * 32 + quad * 8);
                bf16x8 b   = *(const bf16x8*)(vh + (nd * 16 + l15) * 104 + ks * 32 + quad * 8);
                bf16x8 bl8 = *(const bf16x8*)(vl + (nd * 16 + l15) * 104 + ks * 32 + quad * 8);
                acc = __builtin_amdgcn_mfma_f32_16x16x32_bf16(a, b, acc, 0, 0, 0);
                acc = __builtin_amdgcn_mfma_f32_16x16x32_bf16(al8, b, acc, 0, 0, 0);
                acc = __builtin_amdgcn_mfma_f32_16x16x32_bf16(a, bl8, acc, 0, 0, 0);
            }
            int dd = nd * 16 + l15, sbase = mq * 16 + quad * 4;
            float o[4];
            #pragma unroll
            for (int reg = 0; reg < 4; ++reg) {
                int qs = sbase + reg;
                o[reg] = (qs < 66) ? acc[reg] * inv[qs] : 0.f;   // zero K-pad
            }
            uint2 pk;
            pk.x = cvtpk(o[0], o[1]);
            pk.y = cvtpk(o[2], o[3]);
            *(uint2*)(smem + AOT_OFF + dd * 208 + 2 * sbase) = pk;
        }
        // zero aoT cols 80..103
        for (int u = tid; u < 384; u += 256) {
            int row = u / 12, kcol = 80 + 2 * (u % 12);
            *(unsigned*)(smem + AOT_OFF + row * 208 + 2 * kcol) = 0u;
        }
    }
    __syncthreads();

    // ---------------- Stage Wc hi/lo (overlays dead vT) ------------------------------
    if constexpr (PRESPLIT) {
        const unsigned char* wc = ws + WSWC_OFF;   // pre-built 13,312B image (zero-padded)
        for (int i = wid; i < 13; i += 4)
            gload16(wc + (i << 10) + (lane << 4), smem + WCH_OFF + (i << 10));
    } else {
        for (int u = tid; u < 726; u += 256) {           // 22 rows x 33 float2
            int row = u / 33, cp = u - row * 33;
            float2 w = *(const float2*)(Wc + row * 66 + 2 * cp);
            unsigned hi, lo;
            split2(w.x, w.y, hi, lo);
            *(unsigned*)(smem + WCH_OFF + row * 208 + 4 * cp) = hi;
            *(unsigned*)(smem + WCL_OFF + row * 208 + 4 * cp) = lo;
        }
        for (int u = tid; u < 836; u += 256) {           // zero cols 66..103, rows 0..21
            int comp = u >= 418 ? 1 : 0, rem = comp ? u - 418 : u;
            int row = rem / 19, kcol = 66 + 2 * (rem % 19);
            *(unsigned*)(smem + (comp ? WCL_OFF : WCH_OFF) + row * 208 + 2 * kcol) = 0u;
        }
    }
    __syncthreads();

    // ---------------- Phase 6: out = Wc @ ao + bc via MFMA ---------------------------
    {
        const short* Wch = (const short*)(smem + WCH_OFF);
        const short* Wcl = (const short*)(smem + WCL_OFF);
        const short* aoT = (const short*)(smem + AOT_OFF);
        int mj = wid >> 1, nd = wid & 1;
        f32x4 acc = (f32x4){0.f, 0.f, 0.f, 0.f};
        #pragma unroll
        for (int ks = 0; ks < 3; ++ks) {
            bf16x8 a   = *(const bf16x8*)(Wch + (mj * 16 + l15) * 104 + ks * 32 + quad * 8);
            bf16x8 al8 = *(const bf16x8*)(Wcl + (mj * 16 + l15) * 104 + ks * 32 + quad * 8);
            bf16x8 b   = *(const bf16x8*)(aoT + (nd * 16 + l15) * 104 + ks * 32 + quad * 8);
            acc = __builtin_amdgcn_mfma_f32_16x16x32_bf16(a, b, acc, 0, 0, 0);
            acc = __builtin_amdgcn_mfma_f32_16x16x32_bf16(al8, b, acc, 0, 0, 0);
        }
        int dd = nd * 16 + l15;
        #pragma unroll
        for (int reg = 0; reg < 4; ++reg) {
            int j = mj * 16 + quad * 4 + reg;
            if (j < 22) {
                size_t o = (size_t)(bt * J + j) * (H * D) + h * 32 + dd;
                out[o] = acc[reg] + bc[j];
            }
        }
    }
}

extern "C" void kernel_launch(void* const* d_in, const int* in_sizes, int n_in,
                              void* d_out, int out_size, void* d_ws, size_t ws_size,
                              hipStream_t stream) {
    const float* x  = (const float*)d_in[0];
    const float* Wq = (const float*)d_in[1];
    const float* bq = (const float*)d_in[2];
    const float* Wk = (const float*)d_in[3];
    const float* bk = (const float*)d_in[4];
    const float* Wv = (const float*)d_in[5];
    const float* bv = (const float*)d_in[6];
    const float* Wc = (const float*)d_in[7];
    const float* bc = (const float*)d_in[8];
    float* out = (float*)d_out;

    const int B = 512;
    dim3 grid(B * T * H), block(256);
    if (d_ws != nullptr && ws_size >= (size_t)WS_BYTES) {
        hipLaunchKernelGGL(presplit_kernel, dim3(199), dim3(256), 0, stream,
                           Wq, Wk, Wv, Wc, (unsigned char*)d_ws);
        hipLaunchKernelGGL((mha_fused_kernel<true>), grid, block, 0, stream,
                           x, Wq, bq, Wk, bk, Wv, bv, Wc, bc,
                           (const unsigned char*)d_ws, out);
    } else {
        hipLaunchKernelGGL((mha_fused_kernel<false>), grid, block, 0, stream,
                           x, Wq, bq, Wk, bk, Wv, bv, Wc, bc,
                           (const unsigned char*)nullptr, out);
    }
}

// Round 2
// 974.037 us; speedup vs baseline: 1.3844x; 1.1161x over previous
//
#include <hip/hip_runtime.h>
#include <hip/hip_bf16.h>

// R2 theory: VALU still 40% (MFMA 17%, HBM 12%) — dominated by the x-tile split-bf16
// conversion recomputed once per head (8x per (b,t)) + ds_write staging. FETCH=812MB
// (~4x the x tensor) shows cross-XCD refetch too.
// 1) presplit_x_kernel: convert x once per (b,t) into gload-ready swizzled hi/lo bf16
//    images in ws (227MB, guarded; falls back to R1 path if ws too small).
// 2) bt-grouping XCD swizzle: 8 heads of one (b,t) -> same XCD -> L2-hit x images.
// Predicted: VALUBusy ~27%, FETCH ~300MB, main dur 929 -> ~700us.

constexpr int T  = 6;
constexpr int S  = 66;    // 3*J
constexpr int IN = 256;
constexpr int H  = 8;
constexpr int D  = 32;
constexpr int J  = 22;
constexpr float NEG = -9e15f;
constexpr float INV_SQRT_D = 0.17677669529663688110f; // 1/sqrt(32)

// ---------------- LDS map (bytes), SMEM 50,008 -> 3 blocks/CU (<=53,248) -------------
// proj stage (per 64-K chunk, x4): xh/xl 72x128B @0/9,216; wh/wl 96x128B @18,432/30,720
//   (end 43,008). Rows XOR-swizzled: byte ^= (row&7)<<4. x rows 66..79 garbage-tolerated
//   (MFMA rows independent; epilogue discards s>=66).
// attn persistent:
//   qh/ql bf16[66][36] @0/4,752     kh/kl @9,504/14,256 (end 19,008)
//   sc f32[66][66] @19,008 (end 36,432)
//   vTh/vTl bf16[32][104] @36,432/43,088 (208B rows, end 49,744)
//   inv f32[66] @49,744 (end 50,008)
// softmax->PV overlays: Ph/Pl bf16[66][104] @0/13,728 (end 27,456); aoT bf16[32][104] @27,456
// phase-6 overlays (vT dead): Wch/Wcl bf16[32][104] @36,432/43,088
#define XH_OFF   0
#define XL_OFF   9216
#define WH_OFF   18432
#define WL_OFF   30720
#define QH_OFF   0
#define QL_OFF   4752
#define KH_OFF   9504
#define KL_OFF   14256
#define SC_OFF   19008
#define VTH_OFF  36432
#define VTL_OFF  43088
#define INV_OFF  49744
#define PH_OFF   0
#define PL_OFF   13728
#define AOT_OFF  27456
#define WCH_OFF  36432
#define WCL_OFF  43088
#define SMEM_BYTES 50008

// ws layout: 32 W images (h*4+chunk) of [hi 96x128B | lo 96x128B] = 24,576 -> 786,432;
// Wc image [hi 32x208B | lo 32x208B] = 13,312 -> end 799,744;
// x images: per bt (3072) 4 chunks x [hi 72x128B | lo 72x128B] = 73,728 -> 227,292,160.
#define WSW_STRIDE 24576
#define WSWC_OFF   786432
#define WS_W       799744ull
#define XIMG_OFF   799744
#define XIMG_BT    73728
#define WS_FULL    (799744ull + 3072ull * 73728ull)

typedef float f32x4  __attribute__((ext_vector_type(4)));
typedef short bf16x8 __attribute__((ext_vector_type(8)));
typedef short s4v    __attribute__((ext_vector_type(4)));

__device__ __forceinline__ unsigned cvtpk(float a, float b) {
    unsigned r;
    asm("v_cvt_pk_bf16_f32 %0, %1, %2" : "=v"(r) : "v"(a), "v"(b));
    return r;   // low16 = bf16(a), high16 = bf16(b), RNE
}
__device__ __forceinline__ float bfh2f(unsigned short h) {
    return __uint_as_float(((unsigned)h) << 16);
}
// split two f32 into packed bf16 hi (rne) and bf16 lo (rne of residual) — 6 VALU
__device__ __forceinline__ void split2(float a, float b, unsigned& hi, unsigned& lo) {
    unsigned h = cvtpk(a, b);
    float ra = a - __uint_as_float(h << 16);
    float rb = b - __uint_as_float(h & 0xffff0000u);
    lo = cvtpk(ra, rb);
    hi = h;
}
// load 8 bf16 from an 8-byte-aligned LDS address as two b64 reads
__device__ __forceinline__ bf16x8 ld_bf16x8_a8(const short* p) {
    s4v a = *(const s4v*)p;
    s4v b = *(const s4v*)(p + 4);
    return __builtin_shufflevector(a, b, 0, 1, 2, 3, 4, 5, 6, 7);
}
// async global->LDS, 16B/lane; lds base wave-uniform (HW adds lane*16)
__device__ __forceinline__ void gload16(const void* g, void* l) {
    __builtin_amdgcn_global_load_lds(
        (const __attribute__((address_space(1))) unsigned*)g,
        (__attribute__((address_space(3))) unsigned*)l, 16, 0, 0);
}

// ---------------- pre-kernel: split W(h,chunk) images + Wc image into ws -------------
__global__ __launch_bounds__(256)
void presplit_kernel(const float* __restrict__ Wq, const float* __restrict__ Wk,
                     const float* __restrict__ Wv, const float* __restrict__ Wc,
                     unsigned char* __restrict__ ws)
{
    int gid = blockIdx.x * 256 + threadIdx.x;
    if (gid < 49152) {                     // 8h x 4chunk x 96rows x 16 col-groups
        int c   = gid & 15;
        int r2  = gid >> 4;
        int row = r2 % 96;
        int r3  = r2 / 96;                 // h*4 + chunk
        int mat = row >> 5, dd = row & 31;
        int chunk = r3 & 3, hh = r3 >> 2;
        const float* Wm = (mat == 0) ? Wq : (mat == 1) ? Wk : Wv;
        float4 v = *(const float4*)(Wm + (size_t)(hh * 32 + dd) * IN + chunk * 64 + c * 4);
        uint2 hi, lo;
        split2(v.x, v.y, hi.x, lo.x);
        split2(v.z, v.w, hi.y, lo.y);
        unsigned base = (unsigned)r3 * WSW_STRIDE;
        unsigned rel  = (unsigned)(((row << 7) + (c << 3)) ^ ((row & 7) << 4));
        *(uint2*)(ws + base + rel)         = hi;
        *(uint2*)(ws + base + 12288 + rel) = lo;
    } else if (gid < 49152 + 1664) {       // Wc image: 32 rows x 52 dword cols (zero-padded)
        int g2  = gid - 49152;
        int row = g2 / 52, cu = g2 - row * 52;
        int c0  = 2 * cu;
        float a = (row < 22 && c0     < 66) ? Wc[row * 66 + c0]     : 0.f;
        float b = (row < 22 && c0 + 1 < 66) ? Wc[row * 66 + c0 + 1] : 0.f;
        unsigned hi, lo;
        split2(a, b, hi, lo);
        *(unsigned*)(ws + WSWC_OFF + row * 208 + 4 * cu)        = hi;
        *(unsigned*)(ws + WSWC_OFF + 6656 + row * 208 + 4 * cu) = lo;
    }
}

// ---------------- pre-kernel: split x into per-(bt,chunk) swizzled images ------------
// 3072 bt x 66 s x 64 col-groups(4 f32) = 12,976,128 threads (50,688 blocks x 256).
// Rows 66..71 of each image left unwritten: gload pulls them but MFMA rows are
// independent and the epilogue discards s>=66.
__global__ __launch_bounds__(256)
void presplit_x_kernel(const float* __restrict__ x, unsigned char* __restrict__ ws)
{
    int gid = blockIdx.x * 256 + threadIdx.x;
    if (gid >= 3072 * 66 * 64) return;
    int c16  = gid & 63;
    int rest = gid >> 6;
    int s  = rest % 66;
    int bt = rest / 66;
    int chunk = c16 >> 4, c = c16 & 15;
    float4 v = *(const float4*)(x + (size_t)(bt * 66 + s) * 256 + c16 * 4);
    uint2 hi, lo;
    split2(v.x, v.y, hi.x, lo.x);
    split2(v.z, v.w, hi.y, lo.y);
    unsigned rel = (unsigned)(((s << 7) + (c << 3)) ^ ((s & 7) << 4));
    unsigned char* img = ws + XIMG_OFF + (size_t)bt * XIMG_BT + chunk * 18432;
    *(uint2*)(img + rel)        = hi;
    *(uint2*)(img + 9216 + rel) = lo;
}

// MODE: 0 = all inline, 1 = W/Wc presplit, 2 = W/Wc + x presplit
template<int MODE>
__global__ __launch_bounds__(256, 3)
void mha_fused_kernel(const float* __restrict__ x,
                      const float* __restrict__ Wq, const float* __restrict__ bq,
                      const float* __restrict__ Wk, const float* __restrict__ bk,
                      const float* __restrict__ Wv, const float* __restrict__ bv,
                      const float* __restrict__ Wc, const float* __restrict__ bc,
                      const unsigned char* __restrict__ ws,
                      float* __restrict__ out)
{
    __shared__ __align__(16) unsigned char smem[SMEM_BYTES];

    const int tid = threadIdx.x;
    // bt-grouping XCD swizzle: dispatch index i -> XCD i%8 (round-robin heuristic).
    // 8 heads of one bt land at indices r, r+8, ..., r+56 (same XCD, adjacent in time).
    const int i0  = blockIdx.x;
    const int h   = (i0 >> 3) & 7;
    const int bt  = (i0 & 7) | ((i0 >> 6) << 3);   // bijective over [0,3072)

    const int wid  = tid >> 6;           // wave 0..3
    const int lane = tid & 63;
    const int l15  = lane & 15;
    const int quad = lane >> 4;
    const int swz  = (l15 & 7) << 4;     // XOR swizzle for 128B-row tiles

    // ---------------- Phase 1: q,k,v projections via split-bf16 MFMA ------------------
    f32x4 accs[8];
    #pragma unroll
    for (int jj = 0; jj < 8; ++jj) accs[jj] = (f32x4){0.f, 0.f, 0.f, 0.f};

    for (int chunk = 0; chunk < 4; ++chunk) {    // K = 4 x 64
        __syncthreads();
        if constexpr (MODE == 2) {
            // both tiles pre-split + pre-swizzled: pure async global->LDS staging
            const unsigned char* ximg = ws + XIMG_OFF + (size_t)bt * XIMG_BT + chunk * 18432;
            const unsigned char* wimg = ws + (unsigned)((h << 2) | chunk) * WSW_STRIDE;
            for (int i = wid; i < 18; i += 4)
                gload16(ximg + (i << 10) + (lane << 4), smem + XH_OFF + (i << 10));
            for (int i = wid; i < 24; i += 4)
                gload16(wimg + (i << 10) + (lane << 4), smem + WH_OFF + (i << 10));
        } else {
            if constexpr (MODE == 1) {
                const unsigned char* wimg = ws + (unsigned)((h << 2) | chunk) * WSW_STRIDE;
                for (int i = wid; i < 24; i += 4)
                    gload16(wimg + (i << 10) + (lane << 4), smem + WH_OFF + (i << 10));
            } else {
                for (int u = tid; u < 1536; u += 256) {   // W slices: 96 x 64, inline split
                    int row = u >> 4, c = u & 15;
                    int mat = row >> 5, dd = row & 31;
                    const float* Wm = (mat == 0) ? Wq : (mat == 1) ? Wk : Wv;
                    float4 v = *(const float4*)(Wm + (size_t)(h * 32 + dd) * IN + chunk * 64 + c * 4);
                    uint2 hi, lo;
                    split2(v.x, v.y, hi.x, lo.x);
                    split2(v.z, v.w, hi.y, lo.y);
                    int rel = ((row << 7) + (c << 3)) ^ ((row & 7) << 4);
                    *(uint2*)(smem + WH_OFF + rel) = hi;
                    *(uint2*)(smem + WL_OFF + rel) = lo;
                }
            }
            // x tile: 66 x 64 f32 -> hi/lo bf16, swizzled 128B rows
            const float* xg = x + (size_t)bt * S * IN + chunk * 64;
            for (int u = tid; u < 1056; u += 256) {
                int s = u >> 4, c = u & 15;
                float4 v = *(const float4*)(xg + (size_t)s * IN + c * 4);
                uint2 hi, lo;
                split2(v.x, v.y, hi.x, lo.x);
                split2(v.z, v.w, hi.y, lo.y);
                int rel = ((s << 7) + (c << 3)) ^ ((s & 7) << 4);
                *(uint2*)(smem + XH_OFF + rel) = hi;
                *(uint2*)(smem + XL_OFF + rel) = lo;
            }
        }
        __syncthreads();

        const unsigned char* sb = smem;
        for (int jj = 0; jj < 8; ++jj) {
            int j = wid + 4 * jj;
            if (j >= 30) break;                      // wave-uniform
            int mat = j / 10, rr = j - mat * 10;
            int mtile = rr >> 1, ntile = rr & 1;
            int abase = XH_OFF + ((mtile * 16 + l15) << 7);
            int bbase = WH_OFF + (((mat << 5) + (ntile << 4) + l15) << 7);
            #pragma unroll
            for (int kk = 0; kk < 2; ++kk) {
                int off = ((quad << 4) + (kk << 6)) ^ swz;
                bf16x8 ah = *(const bf16x8*)(sb + abase + off);
                bf16x8 al = *(const bf16x8*)(sb + abase + 9216 + off);   // XL = XH+9216
                bf16x8 bh = *(const bf16x8*)(sb + bbase + off);
                bf16x8 bl = *(const bf16x8*)(sb + bbase + 12288 + off);  // WL = WH+12288
                accs[jj] = __builtin_amdgcn_mfma_f32_16x16x32_bf16(ah, bh, accs[jj], 0, 0, 0);
                accs[jj] = __builtin_amdgcn_mfma_f32_16x16x32_bf16(ah, bl, accs[jj], 0, 0, 0);
                accs[jj] = __builtin_amdgcn_mfma_f32_16x16x32_bf16(al, bh, accs[jj], 0, 0, 0);
            }
        }
    }
    __syncthreads();   // stage dead; epilogue overwrites it

    // ---------------- Epilogue: q/k -> hi/lo [s][d]; v -> relu, hi/lo transposed [d][s]
    {
        short* qh = (short*)(smem + QH_OFF); short* ql = (short*)(smem + QL_OFF);
        short* kh = (short*)(smem + KH_OFF); short* kl = (short*)(smem + KL_OFF);
        for (int jj = 0; jj < 8; ++jj) {
            int j = wid + 4 * jj;
            if (j >= 30) break;
            int mat = j / 10, rr = j - mat * 10;
            int mtile = rr >> 1, ntile = rr & 1;
            int dd = ntile * 16 + l15;
            const float* bias_p = (mat == 0) ? bq : (mat == 1) ? bk : bv;
            float bias = bias_p[h * 32 + dd];
            int sbase = mtile * 16 + quad * 4;
            if (mat < 2) {
                short* bh_ = (mat == 0) ? qh : kh;
                short* bl_ = (mat == 0) ? ql : kl;
                uint2 hi, lo;
                split2(accs[jj][0] + bias, accs[jj][1] + bias, hi.x, lo.x);
                split2(accs[jj][2] + bias, accs[jj][3] + bias, hi.y, lo.y);
                unsigned hs[4] = { hi.x & 0xffffu, hi.x >> 16, hi.y & 0xffffu, hi.y >> 16 };
                unsigned ls[4] = { lo.x & 0xffffu, lo.x >> 16, lo.y & 0xffffu, lo.y >> 16 };
                #pragma unroll
                for (int reg = 0; reg < 4; ++reg) {
                    int s = sbase + reg;
                    if (s < 66) {
                        bh_[s * 36 + dd] = (short)hs[reg];
                        bl_[s * 36 + dd] = (short)ls[reg];
                    }
                }
            } else {
                float vv[4];
                #pragma unroll
                for (int reg = 0; reg < 4; ++reg) {
                    int s = sbase + reg;
                    vv[reg] = (s < 66) ? fmaxf(accs[jj][reg] + bias, 0.f) : 0.f; // zero K-pad
                }
                uint2 ph, pl;
                split2(vv[0], vv[1], ph.x, pl.x);
                split2(vv[2], vv[3], ph.y, pl.y);
                *(uint2*)(smem + VTH_OFF + dd * 208 + 2 * sbase) = ph;
                *(uint2*)(smem + VTL_OFF + dd * 208 + 2 * sbase) = pl;
            }
        }
        // zero vT cols 80..95 (beyond epilogue coverage; K-pad safety for PV)
        for (int u = tid; u < 512; u += 256) {
            int comp = u >= 256 ? 1 : 0, rem = comp ? u - 256 : u;
            int row = rem >> 3, kcol = 80 + 2 * (rem & 7);
            *(unsigned*)(smem + (comp ? VTL_OFF : VTH_OFF) + row * 208 + 2 * kcol) = 0u;
        }
    }
    __syncthreads();

    // ---------------- Phase 3: sc = mask * (q k^T) / sqrt(D) via split MFMA ----------
    {
        const short* qh = (const short*)(smem + QH_OFF);
        const short* ql = (const short*)(smem + QL_OFF);
        const short* kh = (const short*)(smem + KH_OFF);
        const short* kl = (const short*)(smem + KL_OFF);
        float* sc = (float*)(smem + SC_OFF);
        for (int t = 0; t < 7; ++t) {
            int tt = wid + 4 * t;
            if (tt >= 25) break;                 // wave-uniform
            int mq = tt / 5, mk = tt - mq * 5;
            int aoff = (mq * 16 + l15) * 36 + quad * 8;
            int boff = (mk * 16 + l15) * 36 + quad * 8;
            bf16x8 ah = ld_bf16x8_a8(qh + aoff);
            bf16x8 al = ld_bf16x8_a8(ql + aoff);
            bf16x8 bh = ld_bf16x8_a8(kh + boff);
            bf16x8 bl = ld_bf16x8_a8(kl + boff);
            f32x4 acc = (f32x4){0.f, 0.f, 0.f, 0.f};
            acc = __builtin_amdgcn_mfma_f32_16x16x32_bf16(ah, bh, acc, 0, 0, 0);
            acc = __builtin_amdgcn_mfma_f32_16x16x32_bf16(ah, bl, acc, 0, 0, 0);
            acc = __builtin_amdgcn_mfma_f32_16x16x32_bf16(al, bh, acc, 0, 0, 0);
            int ks = mk * 16 + l15;
            #pragma unroll
            for (int reg = 0; reg < 4; ++reg) {
                int qs = mq * 16 + quad * 4 + reg;
                if (qs < 66 && ks < 66) {
                    bool masked = (qs < J && ks >= 2 * J) || (qs >= 2 * J && ks < J);
                    sc[qs * 66 + ks] = masked ? 0.f : acc[reg] * INV_SQRT_D;
                }
            }
        }
    }
    __syncthreads();

    // ---------------- Phase 4: prune + softmax (16-lane groups, regs + shuffles) ------
    // Group->row remap: rows step by 4 within a wave -> sc reads land on banks {0,8,16,24}.
    {
        const float* sc = (const float*)(smem + SC_OFF);
        const int group = tid >> 4, lane16 = tid & 15;
        const int rbase = ((group & 3) << 2) + (group >> 2);   // bijection over [0,16)
        float val[5][5];
        #pragma unroll
        for (int i = 0; i < 5; ++i) {
            int r = rbase + 16 * i;
            #pragma unroll
            for (int tt = 0; tt < 5; ++tt) {
                int c = lane16 + 16 * tt;
                val[i][tt] = (r < 66 && c < 66) ? sc[r * 66 + c] : -INFINITY;
            }
        }
        __syncthreads();   // all sc reads done -> P may overlay sc front

        short* Ph = (short*)(smem + PH_OFF);
        short* Pl = (short*)(smem + PL_OFF);
        float* inv = (float*)(smem + INV_OFF);
        #pragma unroll
        for (int i = 0; i < 5; ++i) {
            int r = rbase + 16 * i;
            if (r >= 66) continue;               // group-uniform
            float m = -INFINITY;
            #pragma unroll
            for (int tt = 0; tt < 5; ++tt) m = fmaxf(m, val[i][tt]);
            m = fmaxf(m, __shfl_xor(m, 1));
            m = fmaxf(m, __shfl_xor(m, 2));
            m = fmaxf(m, __shfl_xor(m, 4));
            m = fmaxf(m, __shfl_xor(m, 8));
            const float thr = m / 9.0f;
            float e[5], lsum = 0.f, rmax = -INFINITY;
            #pragma unroll
            for (int tt = 0; tt < 5; ++tt) {
                float sv = val[i][tt];
                float pr = (fabsf(sv) <= thr) ? NEG : sv;   // -INF sentinels stay below
                val[i][tt] = pr;
                rmax = fmaxf(rmax, pr);
            }
            rmax = fmaxf(rmax, __shfl_xor(rmax, 1));
            rmax = fmaxf(rmax, __shfl_xor(rmax, 2));
            rmax = fmaxf(rmax, __shfl_xor(rmax, 4));
            rmax = fmaxf(rmax, __shfl_xor(rmax, 8));
            #pragma unroll
            for (int tt = 0; tt < 5; ++tt) {
                int c = lane16 + 16 * tt;
                float ev = (c < 66) ? __expf(val[i][tt] - rmax) : 0.f;
                e[tt] = ev;
                lsum += ev;
            }
            lsum += __shfl_xor(lsum, 1);
            lsum += __shfl_xor(lsum, 2);
            lsum += __shfl_xor(lsum, 4);
            lsum += __shfl_xor(lsum, 8);
            #pragma unroll
            for (int tt = 0; tt < 6; ++tt) {     // cols 0..95: data or zero pad
                int c = lane16 + 16 * tt;
                unsigned short hi = 0, lo = 0;
                if (c < 66) {
                    float ev = e[tt];
                    hi = (unsigned short)cvtpk(ev, ev);
                    lo = (unsigned short)cvtpk(ev - bfh2f(hi), 0.f);
                }
                if (c < 96) {
                    Ph[r * 104 + c] = (short)hi;
                    Pl[r * 104 + c] = (short)lo;
                }
            }
            if (lane16 == 0) inv[r] = 1.0f / lsum;
        }
    }
    __syncthreads();

    // ---------------- Phase 5: aoT = (P @ v)^T * inv, bf16-hi, via MFMA --------------
    {
        const short* Ph = (const short*)(smem + PH_OFF);
        const short* Pl = (const short*)(smem + PL_OFF);
        const short* vh = (const short*)(smem + VTH_OFF);
        const short* vl = (const short*)(smem + VTL_OFF);
        const float* inv = (const float*)(smem + INV_OFF);
        for (int t = 0; t < 3; ++t) {
            int tt = wid + 4 * t;
            if (tt >= 10) break;
            int mq = tt >> 1, nd = tt & 1;
            f32x4 acc = (f32x4){0.f, 0.f, 0.f, 0.f};
            #pragma unroll
            for (int ks = 0; ks < 3; ++ks) {
                bf16x8 a   = *(const bf16x8*)(Ph + (mq * 16 + l15) * 104 + ks * 32 + quad * 8);
                bf16x8 al8 = *(const bf16x8*)(Pl + (mq * 16 + l15) * 104 + ks * 32 + quad * 8);
                bf16x8 b   = *(const bf16x8*)(vh + (nd * 16 + l15) * 104 + ks * 32 + quad * 8);
                bf16x8 bl8 = *(const bf16x8*)(vl + (nd * 16 + l15) * 104 + ks * 32 + quad * 8);
                acc = __builtin_amdgcn_mfma_f32_16x16x32_bf16(a, b, acc, 0, 0, 0);
                acc = __builtin_amdgcn_mfma_f32_16x16x32_bf16(al8, b, acc, 0, 0, 0);
                acc = __builtin_amdgcn_mfma_f32_16x16x32_bf16(a, bl8, acc, 0, 0, 0);
            }
            int dd = nd * 16 + l15, sbase = mq * 16 + quad * 4;
            float o[4];
            #pragma unroll
            for (int reg = 0; reg < 4; ++reg) {
                int qs = sbase + reg;
                o[reg] = (qs < 66) ? acc[reg] * inv[qs] : 0.f;   // zero K-pad
            }
            uint2 pk;
            pk.x = cvtpk(o[0], o[1]);
            pk.y = cvtpk(o[2], o[3]);
            *(uint2*)(smem + AOT_OFF + dd * 208 + 2 * sbase) = pk;
        }
        // zero aoT cols 80..103
        for (int u = tid; u < 384; u += 256) {
            int row = u / 12, kcol = 80 + 2 * (u % 12);
            *(unsigned*)(smem + AOT_OFF + row * 208 + 2 * kcol) = 0u;
        }
    }
    __syncthreads();

    // ---------------- Stage Wc hi/lo (overlays dead vT) ------------------------------
    if constexpr (MODE >= 1) {
        const unsigned char* wc = ws + WSWC_OFF;   // pre-built 13,312B image (zero-padded)
        for (int i = wid; i < 13; i += 4)
            gload16(wc + (i << 10) + (lane << 4), smem + WCH_OFF + (i << 10));
    } else {
        for (int u = tid; u < 726; u += 256) {           // 22 rows x 33 float2
            int row = u / 33, cp = u - row * 33;
            float2 w = *(const float2*)(Wc + row * 66 + 2 * cp);
            unsigned hi, lo;
            split2(w.x, w.y, hi, lo);
            *(unsigned*)(smem + WCH_OFF + row * 208 + 4 * cp) = hi;
            *(unsigned*)(smem + WCL_OFF + row * 208 + 4 * cp) = lo;
        }
        for (int u = tid; u < 836; u += 256) {           // zero cols 66..103, rows 0..21
            int comp = u >= 418 ? 1 : 0, rem = comp ? u - 418 : u;
            int row = rem / 19, kcol = 66 + 2 * (rem % 19);
            *(unsigned*)(smem + (comp ? WCL_OFF : WCH_OFF) + row * 208 + 2 * kcol) = 0u;
        }
    }
    __syncthreads();

    // ---------------- Phase 6: out = Wc @ ao + bc via MFMA ---------------------------
    {
        const short* Wch = (const short*)(smem + WCH_OFF);
        const short* Wcl = (const short*)(smem + WCL_OFF);
        const short* aoT = (const short*)(smem + AOT_OFF);
        int mj = wid >> 1, nd = wid & 1;
        f32x4 acc = (f32x4){0.f, 0.f, 0.f, 0.f};
        #pragma unroll
        for (int ks = 0; ks < 3; ++ks) {
            bf16x8 a   = *(const bf16x8*)(Wch + (mj * 16 + l15) * 104 + ks * 32 + quad * 8);
            bf16x8 al8 = *(const bf16x8*)(Wcl + (mj * 16 + l15) * 104 + ks * 32 + quad * 8);
            bf16x8 b   = *(const bf16x8*)(aoT + (nd * 16 + l15) * 104 + ks * 32 + quad * 8);
            acc = __builtin_amdgcn_mfma_f32_16x16x32_bf16(a, b, acc, 0, 0, 0);
            acc = __builtin_amdgcn_mfma_f32_16x16x32_bf16(al8, b, acc, 0, 0, 0);
        }
        int dd = nd * 16 + l15;
        #pragma unroll
        for (int reg = 0; reg < 4; ++reg) {
            int j = mj * 16 + quad * 4 + reg;
            if (j < 22) {
                size_t o = (size_t)(bt * J + j) * (H * D) + h * 32 + dd;
                out[o] = acc[reg] + bc[j];
            }
        }
    }
}

extern "C" void kernel_launch(void* const* d_in, const int* in_sizes, int n_in,
                              void* d_out, int out_size, void* d_ws, size_t ws_size,
                              hipStream_t stream) {
    const float* x  = (const float*)d_in[0];
    const float* Wq = (const float*)d_in[1];
    const float* bq = (const float*)d_in[2];
    const float* Wk = (const float*)d_in[3];
    const float* bk = (const float*)d_in[4];
    const float* Wv = (const float*)d_in[5];
    const float* bv = (const float*)d_in[6];
    const float* Wc = (const float*)d_in[7];
    const float* bc = (const float*)d_in[8];
    float* out = (float*)d_out;

    const int B = 512;
    dim3 grid(B * T * H), block(256);
    if (d_ws != nullptr && ws_size >= WS_FULL) {
        hipLaunchKernelGGL(presplit_kernel, dim3(199), dim3(256), 0, stream,
                           Wq, Wk, Wv, Wc, (unsigned char*)d_ws);
        hipLaunchKernelGGL(presplit_x_kernel, dim3(50688), dim3(256), 0, stream,
                           x, (unsigned char*)d_ws);
        hipLaunchKernelGGL((mha_fused_kernel<2>), grid, block, 0, stream,
                           x, Wq, bq, Wk, bk, Wv, bv, Wc, bc,
                           (const unsigned char*)d_ws, out);
    } else if (d_ws != nullptr && ws_size >= WS_W) {
        hipLaunchKernelGGL(presplit_kernel, dim3(199), dim3(256), 0, stream,
                           Wq, Wk, Wv, Wc, (unsigned char*)d_ws);
        hipLaunchKernelGGL((mha_fused_kernel<1>), grid, block, 0, stream,
                           x, Wq, bq, Wk, bk, Wv, bv, Wc, bc,
                           (const unsigned char*)d_ws, out);
    } else {
        hipLaunchKernelGGL((mha_fused_kernel<0>), grid, block, 0, stream,
                           x, Wq, bq, Wk, bk, Wv, bv, Wc, bc,
                           (const unsigned char*)nullptr, out);
    }
}